// Round 8
// baseline (184.684 us; speedup 1.0000x reference)
//
#include <hip/hip_runtime.h>
#include <math.h>

#define BATCH 16
#define SEQ 64
#define NKEY 196
#define HIDDEN 1024
#define ATT_FEAT 2048
#define EMBED 512

using short8   = __attribute__((ext_vector_type(8))) short;
using f32x4    = __attribute__((ext_vector_type(4))) float;
using float4v  = __attribute__((ext_vector_type(4))) float;
using uint4v   = __attribute__((ext_vector_type(4))) unsigned;
using ushort4v = __attribute__((ext_vector_type(4))) unsigned short;

// exact truncation split: x = hi + lo + O(2^-16 |x|); bit-ops only
__device__ inline void split8(const float* f, short8& hi, short8& lo) {
    uint4v hp, lp;
    #pragma unroll
    for (int p = 0; p < 4; ++p) {
        unsigned u0 = __builtin_bit_cast(unsigned, f[2 * p + 0]);
        unsigned u1 = __builtin_bit_cast(unsigned, f[2 * p + 1]);
        unsigned m0 = u0 & 0xFFFF0000u;
        unsigned m1 = u1 & 0xFFFF0000u;
        hp[p] = m1 | (u0 >> 16);
        float l0 = f[2 * p + 0] - __builtin_bit_cast(float, m0);
        float l1 = f[2 * p + 1] - __builtin_bit_cast(float, m1);
        unsigned v0 = __builtin_bit_cast(unsigned, l0);
        unsigned v1 = __builtin_bit_cast(unsigned, l1);
        lp[p] = (v1 & 0xFFFF0000u) | (v0 >> 16);
    }
    hi = __builtin_bit_cast(short8, hp);
    lo = __builtin_bit_cast(short8, lp);
}

__device__ inline void split1(float x, unsigned short& h, unsigned short& l) {
    unsigned u = __builtin_bit_cast(unsigned, x);
    unsigned m = u & 0xFFFF0000u;
    h = (unsigned short)(u >> 16);
    float lo = x - __builtin_bit_cast(float, m);
    l = (unsigned short)(__builtin_bit_cast(unsigned, lo) >> 16);
}

// swizzled byte offset within a [row][128B] LDS tile (T2 pattern)
__device__ inline int swz(int row, int kbyte) {
    return row * 128 + (kbyte ^ ((row & 7) << 4));
}

// ---------------------------------------------------------------------------
// One-shot: W [K][N] f32  ->  Th/Tl [N][K] bf16 (truncation hi/lo split).
// ---------------------------------------------------------------------------
__global__ __launch_bounds__(256) void prep_split_transpose(
    const float* __restrict__ W, unsigned short* __restrict__ Th,
    unsigned short* __restrict__ Tl, int K, int N)
{
    __shared__ float tile[32][33];
    const int k0 = blockIdx.x * 32, n0 = blockIdx.y * 32;
    const int tid = threadIdx.x;

    {
        const int kl = tid >> 3;
        const int ng = (tid & 7) * 4;
        float4v v = *(const float4v*)(W + (size_t)(k0 + kl) * N + n0 + ng);
        tile[kl][ng + 0] = v.x; tile[kl][ng + 1] = v.y;
        tile[kl][ng + 2] = v.z; tile[kl][ng + 3] = v.w;
    }
    __syncthreads();
    {
        const int nl = tid >> 3;
        const int kg = (tid & 7) * 4;
        ushort4v h, l;
        #pragma unroll
        for (int j = 0; j < 4; ++j) {
            unsigned short hh, ll;
            split1(tile[kg + j][nl], hh, ll);
            h[j] = hh; l[j] = ll;
        }
        size_t off = (size_t)(n0 + nl) * K + k0 + kg;
        *(ushort4v*)(Th + off) = h;
        *(ushort4v*)(Tl + off) = l;
    }
}

// ---------------------------------------------------------------------------
// Split-bf16 MFMA GEMM: A staged in LDS (double-buffered, hi/lo), B fragments
// loaded DIRECTLY from global (pre-split/transposed [N][K], L2-resident) into
// registers with 1-step prefetch. Tile 64x64, BK=64, 4 waves each a 32x32
// quadrant. 3 MFMA products: hi*hi + hi*lo + lo*hi.
// Requires M%64==0, N%64==0, K%128==0 (nt even), grid%8==0.
// ---------------------------------------------------------------------------
__global__ __launch_bounds__(256) void gemm_mfma_bglob(
    const float* __restrict__ A, const unsigned short* __restrict__ BTh,
    const unsigned short* __restrict__ BTl, const float* __restrict__ bias,
    float* __restrict__ C, int N, int K)
{
    __shared__ __align__(16) unsigned short AsHi[2][64 * 64];
    __shared__ __align__(16) unsigned short AsLo[2][64 * 64];

    const int ncol = N >> 6;
    const int G  = gridDim.x;
    const int hh = blockIdx.x;
    const int t0 = (hh & 7) * (G >> 3) + (hh >> 3);   // XCD-contiguous tiles
    const int row0 = (t0 / ncol) << 6;
    const int col0 = (t0 % ncol) << 6;

    const int tid  = threadIdx.x;
    const int lane = tid & 63;
    const int w    = tid >> 6;
    const int wr   = w >> 1;
    const int wc   = w & 1;
    const int l15  = lane & 15;
    const int lg   = lane >> 4;

    // A staging coords (row=tid>>2, k-chunk=(tid&3)*16 f32)
    const int ar = tid >> 2;
    const int ac = (tid & 3) << 4;
    const float* Arow = A + (size_t)(row0 + ar) * K + ac;

    // per-lane B fragment row bases (element units)
    const size_t bRow0 = (size_t)(col0 + wc * 32 + l15) * K;
    const size_t bRow1 = bRow0 + (size_t)16 * K;
    const int    kfrag = lg << 3;                    // lg*8 elements in 32-k sub

    f32x4 acc[2][2] = {};
    float Af[16];
    short8 bhC[2][2], blC[2][2], bhN[2][2], blN[2][2];   // [ksub][n]

    const int sw0 = swz(ar, ac * 2);
    const int sw1 = swz(ar, ac * 2 + 16);

    auto loadA = [&](int k0) {
        #pragma unroll
        for (int q = 0; q < 4; ++q) {
            float4v v = *(const float4v*)(Arow + k0 + q * 4);
            Af[q*4+0] = v.x; Af[q*4+1] = v.y;
            Af[q*4+2] = v.z; Af[q*4+3] = v.w;
        }
    };
    auto writeA = [&](int c) {
        short8 hi0, hi1, lo0, lo1;
        split8(Af, hi0, lo0);
        split8(Af + 8, hi1, lo1);
        char* AH = (char*)AsHi[c]; char* AL = (char*)AsLo[c];
        *(short8*)(AH + sw0) = hi0;  *(short8*)(AH + sw1) = hi1;
        *(short8*)(AL + sw0) = lo0;  *(short8*)(AL + sw1) = lo1;
    };
    auto loadB = [&](int k0, short8 (&bh)[2][2], short8 (&bl)[2][2]) {
        #pragma unroll
        for (int ks = 0; ks < 2; ++ks) {
            const int ko = k0 + ks * 32 + kfrag;
            bh[ks][0] = *(const short8*)(BTh + bRow0 + ko);
            bh[ks][1] = *(const short8*)(BTh + bRow1 + ko);
            bl[ks][0] = *(const short8*)(BTl + bRow0 + ko);
            bl[ks][1] = *(const short8*)(BTl + bRow1 + ko);
        }
    };
    auto compute = [&](int c, short8 (&bh)[2][2], short8 (&bl)[2][2]) {
        const char* AH = (const char*)AsHi[c];
        const char* AL = (const char*)AsLo[c];
        #pragma unroll
        for (int ks = 0; ks < 2; ++ks) {
            const int kb = ks * 64 + (lg << 4);
            short8 ah[2], al[2];
            #pragma unroll
            for (int m = 0; m < 2; ++m) {
                int off = swz(wr * 32 + m * 16 + l15, kb);
                ah[m] = *(const short8*)(AH + off);
                al[m] = *(const short8*)(AL + off);
            }
            #pragma unroll
            for (int m = 0; m < 2; ++m)
                #pragma unroll
                for (int n = 0; n < 2; ++n) {
                    acc[m][n] = __builtin_amdgcn_mfma_f32_16x16x32_bf16(ah[m], bh[ks][n], acc[m][n], 0, 0, 0);
                    acc[m][n] = __builtin_amdgcn_mfma_f32_16x16x32_bf16(ah[m], bl[ks][n], acc[m][n], 0, 0, 0);
                    acc[m][n] = __builtin_amdgcn_mfma_f32_16x16x32_bf16(al[m], bh[ks][n], acc[m][n], 0, 0, 0);
                }
        }
    };

    const int nt = K >> 6;
    loadA(0); writeA(0);
    loadB(0, bhC, blC);

    for (int t = 0; t < nt; ++t) {
        __syncthreads();
        const int cur = t & 1;
        if (t + 1 < nt) {
            loadA((t + 1) << 6);
            loadB((t + 1) << 6, bhN, blN);
        }
        compute(cur, bhC, blC);
        if (t + 1 < nt) writeA(cur ^ 1);
        #pragma unroll
        for (int ks = 0; ks < 2; ++ks)
            #pragma unroll
            for (int n = 0; n < 2; ++n) {
                bhC[ks][n] = bhN[ks][n];
                blC[ks][n] = blN[ks][n];
            }
    }

    #pragma unroll
    for (int m = 0; m < 2; ++m)
        #pragma unroll
        for (int n = 0; n < 2; ++n)
            #pragma unroll
            for (int v = 0; v < 4; ++v) {
                int r = row0 + wr * 32 + m * 16 + lg * 4 + v;
                int c = col0 + wc * 32 + n * 16 + l15;
                float val = acc[m][n][v];
                if (bias) val += bias[c];
                C[(size_t)r * N + c] = val;
            }
}

// ---------------------------------------------------------------------------
// scores[b,s,n] = 2 * sum_e w[e] * sigmoid(2*(Wh+Uv))  (Sum(w) shift dropped)
// ---------------------------------------------------------------------------
__global__ __launch_bounds__(256) void scores_kernel(
    const float* __restrict__ Wh, const float* __restrict__ Uv,
    const float* __restrict__ wvec, const int* __restrict__ mask,
    float* __restrict__ scores)
{
    const int n0 = blockIdx.x * 16;
    const int s0 = blockIdx.y * 16;
    const int b  = blockIdx.z;
    const int tid = threadIdx.x;
    const int tx = tid & 15;
    const int ty = tid >> 4;

    __shared__ float whs[16][64];
    __shared__ float uvs[16][64];

    const float KC = -2.8853900817779268f;   // -2*log2(e)

    const int r  = tid >> 4;
    const int c4 = tid & 15;
    const int sr = s0 + r;
    const int nr_raw = n0 + r;
    const int nr = nr_raw < NKEY ? nr_raw : NKEY - 1;

    const float* WhRow = Wh + (size_t)(b * SEQ + sr) * EMBED;
    const float* UvRow = Uv + (size_t)(b * NKEY + nr) * EMBED;

    float acc0 = 0.f, acc1 = 0.f, acc2 = 0.f, acc3 = 0.f;

    for (int e0 = 0; e0 < EMBED; e0 += 64) {
        float4v wv = *(const float4v*)(WhRow + e0 + c4 * 4);
        float4v uv = *(const float4v*)(UvRow + e0 + c4 * 4);
        *(float4v*)&whs[r][(c4 ^ r) << 2] = wv;
        *(float4v*)&uvs[r][(c4 ^ r) << 2] = uv;
        __syncthreads();

        #pragma unroll
        for (int c = 0; c < 16; ++c) {
            float4v whv = *(const float4v*)&whs[ty][(c ^ ty) << 2];
            float4v uvv = *(const float4v*)&uvs[tx][(c ^ tx) << 2];
            const float w0 = wvec[e0 + c * 4 + 0];
            const float w1 = wvec[e0 + c * 4 + 1];
            const float w2 = wvec[e0 + c * 4 + 2];
            const float w3 = wvec[e0 + c * 4 + 3];
            float t0 = __builtin_amdgcn_exp2f(KC * (whv.x + uvv.x));
            float t1 = __builtin_amdgcn_exp2f(KC * (whv.y + uvv.y));
            float t2 = __builtin_amdgcn_exp2f(KC * (whv.z + uvv.z));
            float t3 = __builtin_amdgcn_exp2f(KC * (whv.w + uvv.w));
            acc0 = fmaf(w0, __builtin_amdgcn_rcpf(1.f + t0), acc0);
            acc1 = fmaf(w1, __builtin_amdgcn_rcpf(1.f + t1), acc1);
            acc2 = fmaf(w2, __builtin_amdgcn_rcpf(1.f + t2), acc2);
            acc3 = fmaf(w3, __builtin_amdgcn_rcpf(1.f + t3), acc3);
        }
        __syncthreads();
    }

    float sc = 2.f * ((acc0 + acc1) + (acc2 + acc3));
    const int n = n0 + tx;
    if (n < NKEY) {
        float v = (mask[b * NKEY + n] == 0) ? -1e9f : sc;
        scores[(size_t)(b * SEQ + s0 + ty) * NKEY + n] = v;
    }
}

// ---------------------------------------------------------------------------
// In-place row softmax over N=196. One wave per row.
// ---------------------------------------------------------------------------
__global__ __launch_bounds__(64) void softmax_kernel(float* __restrict__ sw)
{
    const int row = blockIdx.x;
    const int lane = threadIdx.x;
    float v[4];
    float mx = -INFINITY;
    #pragma unroll
    for (int k = 0; k < 4; ++k) {
        int n = lane + 64 * k;
        v[k] = (n < NKEY) ? sw[(size_t)row * NKEY + n] : -INFINITY;
        mx = fmaxf(mx, v[k]);
    }
    #pragma unroll
    for (int off = 32; off; off >>= 1) mx = fmaxf(mx, __shfl_xor(mx, off));
    float sum = 0.f;
    #pragma unroll
    for (int k = 0; k < 4; ++k) {
        v[k] = __expf(v[k] - mx);
        if (lane + 64 * k < NKEY) sum += v[k];
    }
    #pragma unroll
    for (int off = 32; off; off >>= 1) sum += __shfl_xor(sum, off);
    const float inv = __fdividef(1.f, sum);
    #pragma unroll
    for (int k = 0; k < 4; ++k) {
        int n = lane + 64 * k;
        if (n < NKEY) sw[(size_t)row * NKEY + n] = v[k] * inv;
    }
}

// ---------------------------------------------------------------------------
// attn[b,s,f] = sum_n weights[b,s,n] * feats[b,n,f]
// 256 threads x float4 = 1024 f-cols, 8 s-rows; weights transposed in LDS.
// ---------------------------------------------------------------------------
__global__ __launch_bounds__(256) void attn_kernel(
    const float* __restrict__ weights, const float* __restrict__ feats,
    float* __restrict__ out)
{
    const int t   = threadIdx.x;
    const int col = blockIdx.x * 1024 + t * 4;
    const int s0  = blockIdx.y * 8;
    const int b   = blockIdx.z;

    __shared__ float wt[NKEY][8];
    for (int i = t; i < 8 * NKEY; i += 256) {
        int s = i / NKEY, n = i % NKEY;
        wt[n][s] = weights[(size_t)(b * SEQ + s0 + s) * NKEY + n];
    }
    __syncthreads();

    const float* fp = feats + (size_t)b * NKEY * ATT_FEAT + col;

    float4v acc[8] = {};
    #pragma unroll 4
    for (int n = 0; n < NKEY; ++n) {
        float4v f  = *(const float4v*)(fp + (size_t)n * ATT_FEAT);
        float4v w0 = *(const float4v*)&wt[n][0];
        float4v w1 = *(const float4v*)&wt[n][4];
        acc[0] += w0.x * f;
        acc[1] += w0.y * f;
        acc[2] += w0.z * f;
        acc[3] += w0.w * f;
        acc[4] += w1.x * f;
        acc[5] += w1.y * f;
        acc[6] += w1.z * f;
        acc[7] += w1.w * f;
    }

    float* op = out + (size_t)(b * SEQ + s0) * ATT_FEAT + col;
    #pragma unroll
    for (int s = 0; s < 8; ++s)
        *(float4v*)(op + (size_t)s * ATT_FEAT) = acc[s];
}

// ---------------------------------------------------------------------------
extern "C" void kernel_launch(void* const* d_in, const int* in_sizes, int n_in,
                              void* d_out, int out_size, void* d_ws, size_t ws_size,
                              hipStream_t stream)
{
    const float* hidden = (const float*)d_in[0];
    const float* feats  = (const float*)d_in[1];
    const int*   mask   = (const int*)  d_in[2];
    const float* w_h    = (const float*)d_in[3];
    const float* w_u    = (const float*)d_in[4];
    const float* bvec   = (const float*)d_in[5];
    const float* wvec   = (const float*)d_in[6];

    float* out         = (float*)d_out;
    float* attn_out    = out;
    float* weights_out = out + (size_t)BATCH * SEQ * ATT_FEAT;

    // workspace layout (~20.4 MB)
    float* Wh = (float*)d_ws;                                   // 1024x512 f32
    float* Uv = Wh + (size_t)BATCH * SEQ * EMBED;               // 3136x512 f32
    unsigned short* WhTh = (unsigned short*)(Uv + (size_t)BATCH * NKEY * EMBED);
    unsigned short* WhTl = WhTh + (size_t)EMBED * HIDDEN;       // [512][1024] bf16
    unsigned short* WuTh = WhTl + (size_t)EMBED * HIDDEN;
    unsigned short* WuTl = WuTh + (size_t)EMBED * ATT_FEAT;     // [512][2048] bf16

    // P1/P2: pre-split + transpose weights (one-shot, memory-bound)
    prep_split_transpose<<<dim3(HIDDEN / 32, EMBED / 32), 256, 0, stream>>>(
        w_h, WhTh, WhTl, HIDDEN, EMBED);
    prep_split_transpose<<<dim3(ATT_FEAT / 32, EMBED / 32), 256, 0, stream>>>(
        w_u, WuTh, WuTl, ATT_FEAT, EMBED);

    // K1: Wh = hidden @ w_h          grid 128 = 8*16
    gemm_mfma_bglob<<<dim3((BATCH * SEQ / 64) * (EMBED / 64)), 256, 0, stream>>>(
        hidden, WhTh, WhTl, nullptr, Wh, EMBED, HIDDEN);

    // K2: Uv = feats @ w_u + b       grid 392 = 8*49
    gemm_mfma_bglob<<<dim3((BATCH * NKEY / 64) * (EMBED / 64)), 256, 0, stream>>>(
        feats, WuTh, WuTl, bvec, Uv, EMBED, ATT_FEAT);

    // K3: scores (+mask) -> weights region of d_out
    scores_kernel<<<dim3((NKEY + 15) / 16, SEQ / 16, BATCH), 256, 0, stream>>>(
        Wh, Uv, wvec, mask, weights_out);

    // K4: softmax in place
    softmax_kernel<<<dim3(BATCH * SEQ), 64, 0, stream>>>(weights_out);

    // K5: attn_feats = weights @ feats
    attn_kernel<<<dim3(ATT_FEAT / 1024, SEQ / 8, BATCH), 256, 0, stream>>>(
        weights_out, feats, attn_out);
}

// Round 9
// 129.878 us; speedup vs baseline: 1.4220x; 1.4220x over previous
//
#include <hip/hip_runtime.h>
#include <math.h>

#define BATCH 16
#define SEQ 64
#define NKEY 196
#define HIDDEN 1024
#define ATT_FEAT 2048
#define EMBED 512

using short8   = __attribute__((ext_vector_type(8))) short;
using f32x4    = __attribute__((ext_vector_type(4))) float;
using f32x16   = __attribute__((ext_vector_type(16))) float;
using float4v  = __attribute__((ext_vector_type(4))) float;
using uint4v   = __attribute__((ext_vector_type(4))) unsigned;

// exact truncation split: x = hi + lo + O(2^-16 |x|); bit-ops only
__device__ inline void split8(const float* f, short8& hi, short8& lo) {
    uint4v hp, lp;
    #pragma unroll
    for (int p = 0; p < 4; ++p) {
        unsigned u0 = __builtin_bit_cast(unsigned, f[2 * p + 0]);
        unsigned u1 = __builtin_bit_cast(unsigned, f[2 * p + 1]);
        unsigned m0 = u0 & 0xFFFF0000u;
        unsigned m1 = u1 & 0xFFFF0000u;
        hp[p] = m1 | (u0 >> 16);
        float l0 = f[2 * p + 0] - __builtin_bit_cast(float, m0);
        float l1 = f[2 * p + 1] - __builtin_bit_cast(float, m1);
        unsigned v0 = __builtin_bit_cast(unsigned, l0);
        unsigned v1 = __builtin_bit_cast(unsigned, l1);
        lp[p] = (v1 & 0xFFFF0000u) | (v0 >> 16);
    }
    hi = __builtin_bit_cast(short8, hp);
    lo = __builtin_bit_cast(short8, lp);
}

// async global->LDS, 16B per lane; dest = uniform base + lane*16
__device__ __forceinline__ void gl_lds16(const unsigned short* g, unsigned short* l) {
    __builtin_amdgcn_global_load_lds(
        (const __attribute__((address_space(1))) unsigned int*)g,
        (__attribute__((address_space(3))) unsigned int*)l, 16, 0, 0);
}

// ---------------------------------------------------------------------------
// prep_a: A [M][K] f32 -> Th/Tl tiled bf16 (trunc hi/lo split).
// Tile (tm,tk)=64x64; within tile: [ksub(4)][khalf(2)][row(64)][8 bf16]
// == exact LDS image for global_load_lds staging + conflict-free 32x32 frags.
// Grid (M/64, K/64), 256 threads.
// ---------------------------------------------------------------------------
__global__ __launch_bounds__(256) void prep_a_tiled(
    const float* __restrict__ A, unsigned short* __restrict__ Th,
    unsigned short* __restrict__ Tl, int K)
{
    const int tm = blockIdx.x, tk = blockIdx.y;
    const int t = threadIdx.x;
    const int r  = t >> 2;           // row 0..63
    const int ks = t & 3;            // ksub
    const float* src = A + (size_t)(tm * 64 + r) * K + tk * 64 + ks * 16;
    float f[16];
    #pragma unroll
    for (int q = 0; q < 4; ++q) {
        float4v v = *(const float4v*)(src + q * 4);
        f[q*4+0] = v.x; f[q*4+1] = v.y; f[q*4+2] = v.z; f[q*4+3] = v.w;
    }
    const size_t base = ((size_t)tm * (K >> 6) + tk) * 4096;
    #pragma unroll
    for (int khf = 0; khf < 2; ++khf) {
        short8 hi, lo;
        split8(f + khf * 8, hi, lo);
        size_t off = base + (size_t)(ks * 2 + khf) * 512 + r * 8;
        *(short8*)(Th + off) = hi;
        *(short8*)(Tl + off) = lo;
    }
}

// ---------------------------------------------------------------------------
// prep_b: W [K][N] f32 -> Th/Tl tiled bf16, TRANSPOSED to [col][k] tiles.
// Tile (tn,tk); within: [ksub][khalf][col(64)][8]. Grid (N/64, K/64).
// ---------------------------------------------------------------------------
__global__ __launch_bounds__(256) void prep_b_tiled(
    const float* __restrict__ W, unsigned short* __restrict__ Th,
    unsigned short* __restrict__ Tl, int K, int N)
{
    __shared__ float tile[64][65];
    const int tn = blockIdx.x, tk = blockIdx.y;
    const int t = threadIdx.x;
    {
        const int kr = t >> 2;
        const int nc = (t & 3) * 16;
        const float* src = W + (size_t)(tk * 64 + kr) * N + tn * 64 + nc;
        #pragma unroll
        for (int q = 0; q < 4; ++q) {
            float4v v = *(const float4v*)(src + q * 4);
            tile[kr][nc + q*4 + 0] = v.x; tile[kr][nc + q*4 + 1] = v.y;
            tile[kr][nc + q*4 + 2] = v.z; tile[kr][nc + q*4 + 3] = v.w;
        }
    }
    __syncthreads();
    {
        const int c  = t >> 2;
        const int ks = t & 3;
        const size_t base = ((size_t)tn * (K >> 6) + tk) * 4096;
        #pragma unroll
        for (int khf = 0; khf < 2; ++khf) {
            float f[8];
            #pragma unroll
            for (int j = 0; j < 8; ++j)
                f[j] = tile[ks * 16 + khf * 8 + j][c];
            short8 hi, lo;
            split8(f, hi, lo);
            size_t off = base + (size_t)(ks * 2 + khf) * 512 + c * 8;
            *(short8*)(Th + off) = hi;
            *(short8*)(Tl + off) = lo;
        }
    }
}

// ---------------------------------------------------------------------------
// Split-bf16 MFMA GEMM v3: both operands pre-split/tiled; staging is pure
// global_load_lds (width 16); 32x32x16 MFMA; counted-vmcnt double buffer.
// Block 64x64, BK=64, 4 waves each one 32x32 quadrant, 3 products.
// Grid = (M/64)*(N/64), %8==0, XCD-bijective swizzle.
// ---------------------------------------------------------------------------
__global__ __launch_bounds__(256) void gemm_mfma_t32(
    const unsigned short* __restrict__ Ah, const unsigned short* __restrict__ Al,
    const unsigned short* __restrict__ Bh, const unsigned short* __restrict__ Bl,
    const float* __restrict__ bias, float* __restrict__ C,
    int N, int K)
{
    __shared__ __align__(16) unsigned short L[4][2][4096];   // Ah,Al,Bh,Bl x dbuf = 64KB

    const int ktiles = K >> 6;
    const int ncol = N >> 6;
    const int G  = gridDim.x;
    const int hh = blockIdx.x;
    const int t0 = (hh & 7) * (G >> 3) + (hh >> 3);
    const int rt = t0 / ncol, ct = t0 % ncol;

    const int tid = threadIdx.x, lane = tid & 63, w = tid >> 6;
    const int wr = w >> 1, wc = w & 1;
    const int l31 = lane & 31, kh = lane >> 5;

    // each wave stages exactly one of the 4 arrays
    const unsigned short* srcMat = (w == 0) ? Ah : (w == 1) ? Al : (w == 2) ? Bh : Bl;
    const int majorTile = (w < 2) ? rt : ct;
    const unsigned short* src0 = srcMat + (size_t)majorTile * ktiles * 4096 + lane * 8;

    f32x16 acc = {};

    auto stage = [&](int buf, int t) {
        const unsigned short* s = src0 + (size_t)t * 4096;
        unsigned short* d = &L[w][buf][0];
        #pragma unroll
        for (int c = 0; c < 8; ++c)
            gl_lds16(s + c * 512, d + c * 512);
    };

    auto compute = [&](int buf) {
        #pragma unroll
        for (int s = 0; s < 4; ++s) {
            const int offA = ((s * 2 + kh) * 64 + wr * 32 + l31) * 8;
            const int offB = ((s * 2 + kh) * 64 + wc * 32 + l31) * 8;
            short8 ah = *(const short8*)&L[0][buf][offA];
            short8 al = *(const short8*)&L[1][buf][offA];
            short8 bh = *(const short8*)&L[2][buf][offB];
            short8 bl = *(const short8*)&L[3][buf][offB];
            acc = __builtin_amdgcn_mfma_f32_32x32x16_bf16(ah, bh, acc, 0, 0, 0);
            acc = __builtin_amdgcn_mfma_f32_32x32x16_bf16(ah, bl, acc, 0, 0, 0);
            acc = __builtin_amdgcn_mfma_f32_32x32x16_bf16(al, bh, acc, 0, 0, 0);
        }
    };

    const int nt = ktiles;
    stage(0, 0);
    for (int t = 0; t < nt; ++t) {
        const int cur = t & 1;
        if (t + 1 < nt) {
            stage(cur ^ 1, t + 1);
            asm volatile("s_waitcnt vmcnt(8)" ::: "memory");
        } else {
            asm volatile("s_waitcnt vmcnt(0)" ::: "memory");
        }
        __builtin_amdgcn_s_barrier();
        __builtin_amdgcn_sched_barrier(0);
        compute(cur);
        __builtin_amdgcn_sched_barrier(0);
        __builtin_amdgcn_s_barrier();
    }

    // epilogue: 32x32 C/D layout: col=lane&31, row=(reg&3)+8*(reg>>2)+4*(lane>>5)
    const int row0 = rt * 64 + wr * 32;
    const int colg = ct * 64 + wc * 32 + l31;
    const float bv = bias ? bias[colg] : 0.f;
    #pragma unroll
    for (int r = 0; r < 16; ++r) {
        const int row = (r & 3) + 8 * (r >> 2) + 4 * kh;
        C[(size_t)(row0 + row) * N + colg] = acc[r] + bv;
    }
}

// ---------------------------------------------------------------------------
// scores[b,s,n] = 2 * sum_e w[e] * sigmoid(2*(Wh+Uv))  (Sum(w) shift dropped)
// ---------------------------------------------------------------------------
__global__ __launch_bounds__(256) void scores_kernel(
    const float* __restrict__ Wh, const float* __restrict__ Uv,
    const float* __restrict__ wvec, const int* __restrict__ mask,
    float* __restrict__ scores)
{
    const int n0 = blockIdx.x * 16;
    const int s0 = blockIdx.y * 16;
    const int b  = blockIdx.z;
    const int tid = threadIdx.x;
    const int tx = tid & 15;
    const int ty = tid >> 4;

    __shared__ float whs[16][64];
    __shared__ float uvs[16][64];

    const float KC = -2.8853900817779268f;   // -2*log2(e)

    const int r  = tid >> 4;
    const int c4 = tid & 15;
    const int sr = s0 + r;
    const int nr_raw = n0 + r;
    const int nr = nr_raw < NKEY ? nr_raw : NKEY - 1;

    const float* WhRow = Wh + (size_t)(b * SEQ + sr) * EMBED;
    const float* UvRow = Uv + (size_t)(b * NKEY + nr) * EMBED;

    float acc0 = 0.f, acc1 = 0.f, acc2 = 0.f, acc3 = 0.f;

    for (int e0 = 0; e0 < EMBED; e0 += 64) {
        float4v wv = *(const float4v*)(WhRow + e0 + c4 * 4);
        float4v uv = *(const float4v*)(UvRow + e0 + c4 * 4);
        *(float4v*)&whs[r][(c4 ^ r) << 2] = wv;
        *(float4v*)&uvs[r][(c4 ^ r) << 2] = uv;
        __syncthreads();

        #pragma unroll
        for (int c = 0; c < 16; ++c) {
            float4v whv = *(const float4v*)&whs[ty][(c ^ ty) << 2];
            float4v uvv = *(const float4v*)&uvs[tx][(c ^ tx) << 2];
            const float w0 = wvec[e0 + c * 4 + 0];
            const float w1 = wvec[e0 + c * 4 + 1];
            const float w2 = wvec[e0 + c * 4 + 2];
            const float w3 = wvec[e0 + c * 4 + 3];
            float t0 = __builtin_amdgcn_exp2f(KC * (whv.x + uvv.x));
            float t1 = __builtin_amdgcn_exp2f(KC * (whv.y + uvv.y));
            float t2 = __builtin_amdgcn_exp2f(KC * (whv.z + uvv.z));
            float t3 = __builtin_amdgcn_exp2f(KC * (whv.w + uvv.w));
            acc0 = fmaf(w0, __builtin_amdgcn_rcpf(1.f + t0), acc0);
            acc1 = fmaf(w1, __builtin_amdgcn_rcpf(1.f + t1), acc1);
            acc2 = fmaf(w2, __builtin_amdgcn_rcpf(1.f + t2), acc2);
            acc3 = fmaf(w3, __builtin_amdgcn_rcpf(1.f + t3), acc3);
        }
        __syncthreads();
    }

    float sc = 2.f * ((acc0 + acc1) + (acc2 + acc3));
    const int n = n0 + tx;
    if (n < NKEY) {
        float v = (mask[b * NKEY + n] == 0) ? -1e9f : sc;
        scores[(size_t)(b * SEQ + s0 + ty) * NKEY + n] = v;
    }
}

// ---------------------------------------------------------------------------
// In-place row softmax over N=196. One wave per row.
// ---------------------------------------------------------------------------
__global__ __launch_bounds__(64) void softmax_kernel(float* __restrict__ sw)
{
    const int row = blockIdx.x;
    const int lane = threadIdx.x;
    float v[4];
    float mx = -INFINITY;
    #pragma unroll
    for (int k = 0; k < 4; ++k) {
        int n = lane + 64 * k;
        v[k] = (n < NKEY) ? sw[(size_t)row * NKEY + n] : -INFINITY;
        mx = fmaxf(mx, v[k]);
    }
    #pragma unroll
    for (int off = 32; off; off >>= 1) mx = fmaxf(mx, __shfl_xor(mx, off));
    float sum = 0.f;
    #pragma unroll
    for (int k = 0; k < 4; ++k) {
        v[k] = __expf(v[k] - mx);
        if (lane + 64 * k < NKEY) sum += v[k];
    }
    #pragma unroll
    for (int off = 32; off; off >>= 1) sum += __shfl_xor(sum, off);
    const float inv = __fdividef(1.f, sum);
    #pragma unroll
    for (int k = 0; k < 4; ++k) {
        int n = lane + 64 * k;
        if (n < NKEY) sw[(size_t)row * NKEY + n] = v[k] * inv;
    }
}

// ---------------------------------------------------------------------------
// attn[b,s,f] = sum_n weights[b,s,n] * feats[b,n,f]
// ---------------------------------------------------------------------------
__global__ __launch_bounds__(256) void attn_kernel(
    const float* __restrict__ weights, const float* __restrict__ feats,
    float* __restrict__ out)
{
    const int t   = threadIdx.x;
    const int col = blockIdx.x * 1024 + t * 4;
    const int s0  = blockIdx.y * 8;
    const int b   = blockIdx.z;

    __shared__ float wt[NKEY][8];
    for (int i = t; i < 8 * NKEY; i += 256) {
        int s = i / NKEY, n = i % NKEY;
        wt[n][s] = weights[(size_t)(b * SEQ + s0 + s) * NKEY + n];
    }
    __syncthreads();

    const float* fp = feats + (size_t)b * NKEY * ATT_FEAT + col;

    float4v acc[8] = {};
    #pragma unroll 4
    for (int n = 0; n < NKEY; ++n) {
        float4v f  = *(const float4v*)(fp + (size_t)n * ATT_FEAT);
        float4v w0 = *(const float4v*)&wt[n][0];
        float4v w1 = *(const float4v*)&wt[n][4];
        acc[0] += w0.x * f;
        acc[1] += w0.y * f;
        acc[2] += w0.z * f;
        acc[3] += w0.w * f;
        acc[4] += w1.x * f;
        acc[5] += w1.y * f;
        acc[6] += w1.z * f;
        acc[7] += w1.w * f;
    }

    float* op = out + (size_t)(b * SEQ + s0) * ATT_FEAT + col;
    #pragma unroll
    for (int s = 0; s < 8; ++s)
        *(float4v*)(op + (size_t)s * ATT_FEAT) = acc[s];
}

// ---------------------------------------------------------------------------
extern "C" void kernel_launch(void* const* d_in, const int* in_sizes, int n_in,
                              void* d_out, int out_size, void* d_ws, size_t ws_size,
                              hipStream_t stream)
{
    const float* hidden = (const float*)d_in[0];
    const float* feats  = (const float*)d_in[1];
    const int*   mask   = (const int*)  d_in[2];
    const float* w_h    = (const float*)d_in[3];
    const float* w_u    = (const float*)d_in[4];
    const float* bvec   = (const float*)d_in[5];
    const float* wvec   = (const float*)d_in[6];

    float* out         = (float*)d_out;
    float* attn_out    = out;
    float* weights_out = out + (size_t)BATCH * SEQ * ATT_FEAT;

    // workspace layout (~45 MB)
    float* Wh = (float*)d_ws;                                   // 1024x512 f32
    float* Uv = Wh + (size_t)BATCH * SEQ * EMBED;               // 3136x512 f32
    unsigned short* FAh = (unsigned short*)(Uv + (size_t)BATCH * NKEY * EMBED);
    unsigned short* FAl = FAh + (size_t)BATCH * NKEY * ATT_FEAT;   // feats hi/lo
    unsigned short* HAh = FAl + (size_t)BATCH * NKEY * ATT_FEAT;
    unsigned short* HAl = HAh + (size_t)BATCH * SEQ * HIDDEN;      // hidden hi/lo
    unsigned short* UBh = HAl + (size_t)BATCH * SEQ * HIDDEN;
    unsigned short* UBl = UBh + (size_t)EMBED * ATT_FEAT;          // w_u hi/lo
    unsigned short* HBh = UBl + (size_t)EMBED * ATT_FEAT;
    unsigned short* HBl = HBh + (size_t)EMBED * HIDDEN;            // w_h hi/lo

    // prep: split + tile all operands (one-shot, memory-bound)
    prep_a_tiled<<<dim3(BATCH * SEQ / 64, HIDDEN / 64), 256, 0, stream>>>(
        hidden, HAh, HAl, HIDDEN);
    prep_a_tiled<<<dim3(BATCH * NKEY / 64, ATT_FEAT / 64), 256, 0, stream>>>(
        feats, FAh, FAl, ATT_FEAT);
    prep_b_tiled<<<dim3(EMBED / 64, HIDDEN / 64), 256, 0, stream>>>(
        w_h, HBh, HBl, HIDDEN, EMBED);
    prep_b_tiled<<<dim3(EMBED / 64, ATT_FEAT / 64), 256, 0, stream>>>(
        w_u, UBh, UBl, ATT_FEAT, EMBED);

    // K1: Wh = hidden @ w_h     grid 128 = 8*16
    gemm_mfma_t32<<<dim3((BATCH * SEQ / 64) * (EMBED / 64)), 256, 0, stream>>>(
        HAh, HAl, HBh, HBl, nullptr, Wh, EMBED, HIDDEN);

    // K2: Uv = feats @ w_u + b  grid 392 = 8*49
    gemm_mfma_t32<<<dim3((BATCH * NKEY / 64) * (EMBED / 64)), 256, 0, stream>>>(
        FAh, FAl, UBh, UBl, bvec, Uv, EMBED, ATT_FEAT);

    // scores (+mask) -> weights region of d_out
    scores_kernel<<<dim3((NKEY + 15) / 16, SEQ / 16, BATCH), 256, 0, stream>>>(
        Wh, Uv, wvec, mask, weights_out);

    // softmax in place
    softmax_kernel<<<dim3(BATCH * SEQ), 64, 0, stream>>>(weights_out);

    // attn_feats = weights @ feats
    attn_kernel<<<dim3(ATT_FEAT / 1024, SEQ / 8, BATCH), 256, 0, stream>>>(
        weights_out, feats, attn_out);
}

// Round 10
// 123.730 us; speedup vs baseline: 1.4926x; 1.0497x over previous
//
#include <hip/hip_runtime.h>
#include <math.h>

#define BATCH 16
#define SEQ 64
#define NKEY 196
#define HIDDEN 1024
#define ATT_FEAT 2048
#define EMBED 512

using short8   = __attribute__((ext_vector_type(8))) short;
using f32x4    = __attribute__((ext_vector_type(4))) float;
using f32x16   = __attribute__((ext_vector_type(16))) float;
using float4v  = __attribute__((ext_vector_type(4))) float;
using uint4v   = __attribute__((ext_vector_type(4))) unsigned;

#define KCONST (-2.8853900817779268f)   // -2*log2(e)
#define LOG2E  (1.4426950408889634f)

// exact truncation split: x = hi + lo + O(2^-16 |x|); bit-ops only
__device__ inline void split8(const float* f, short8& hi, short8& lo) {
    uint4v hp, lp;
    #pragma unroll
    for (int p = 0; p < 4; ++p) {
        unsigned u0 = __builtin_bit_cast(unsigned, f[2 * p + 0]);
        unsigned u1 = __builtin_bit_cast(unsigned, f[2 * p + 1]);
        unsigned m0 = u0 & 0xFFFF0000u;
        unsigned m1 = u1 & 0xFFFF0000u;
        hp[p] = m1 | (u0 >> 16);
        float l0 = f[2 * p + 0] - __builtin_bit_cast(float, m0);
        float l1 = f[2 * p + 1] - __builtin_bit_cast(float, m1);
        unsigned v0 = __builtin_bit_cast(unsigned, l0);
        unsigned v1 = __builtin_bit_cast(unsigned, l1);
        lp[p] = (v1 & 0xFFFF0000u) | (v0 >> 16);
    }
    hi = __builtin_bit_cast(short8, hp);
    lo = __builtin_bit_cast(short8, lp);
}

// async global->LDS, 16B per lane; dest = uniform base + lane*16
__device__ __forceinline__ void gl_lds16(const unsigned short* g, unsigned short* l) {
    __builtin_amdgcn_global_load_lds(
        (const __attribute__((address_space(1))) unsigned int*)g,
        (__attribute__((address_space(3))) unsigned int*)l, 16, 0, 0);
}

// ---------------------------------------------------------------------------
// prep bodies: produce tiled bf16 hi/lo images.
// Tile 64x64; layout per tile: [ksub(4)][khalf(2)][row(64)][8 bf16] = 4096 sh.
// ---------------------------------------------------------------------------
__device__ inline void prep_a_body(
    const float* __restrict__ A, unsigned short* __restrict__ Th,
    unsigned short* __restrict__ Tl, int K, int tm, int tk, int t)
{
    const int r  = t >> 2;
    const int ks = t & 3;
    const float* src = A + (size_t)(tm * 64 + r) * K + tk * 64 + ks * 16;
    float f[16];
    #pragma unroll
    for (int q = 0; q < 4; ++q) {
        float4v v = *(const float4v*)(src + q * 4);
        f[q*4+0] = v.x; f[q*4+1] = v.y; f[q*4+2] = v.z; f[q*4+3] = v.w;
    }
    const size_t base = ((size_t)tm * (K >> 6) + tk) * 4096;
    #pragma unroll
    for (int khf = 0; khf < 2; ++khf) {
        short8 hi, lo;
        split8(f + khf * 8, hi, lo);
        size_t off = base + (size_t)(ks * 2 + khf) * 512 + r * 8;
        *(short8*)(Th + off) = hi;
        *(short8*)(Tl + off) = lo;
    }
}

__device__ inline void prep_b_body(
    const float* __restrict__ W, unsigned short* __restrict__ Th,
    unsigned short* __restrict__ Tl, int K, int N, int tn, int tk, int t,
    float (*tile)[65])
{
    {
        const int kr = t >> 2;
        const int nc = (t & 3) * 16;
        const float* src = W + (size_t)(tk * 64 + kr) * N + tn * 64 + nc;
        #pragma unroll
        for (int q = 0; q < 4; ++q) {
            float4v v = *(const float4v*)(src + q * 4);
            tile[kr][nc + q*4 + 0] = v.x; tile[kr][nc + q*4 + 1] = v.y;
            tile[kr][nc + q*4 + 2] = v.z; tile[kr][nc + q*4 + 3] = v.w;
        }
    }
    __syncthreads();
    {
        const int c  = t >> 2;
        const int ks = t & 3;
        const size_t base = ((size_t)tn * (K >> 6) + tk) * 4096;
        #pragma unroll
        for (int khf = 0; khf < 2; ++khf) {
            float f[8];
            #pragma unroll
            for (int j = 0; j < 8; ++j)
                f[j] = tile[ks * 16 + khf * 8 + j][c];
            short8 hi, lo;
            split8(f, hi, lo);
            size_t off = base + (size_t)(ks * 2 + khf) * 512 + c * 8;
            *(short8*)(Th + off) = hi;
            *(short8*)(Tl + off) = lo;
        }
    }
}

// one dispatch for all four preps; branch on flat blockIdx (uniform per block)
__global__ __launch_bounds__(256) void uber_prep(
    const float* __restrict__ hidden, const float* __restrict__ feats,
    const float* __restrict__ w_h, const float* __restrict__ w_u,
    unsigned short* HAh, unsigned short* HAl,
    unsigned short* FAh, unsigned short* FAl,
    unsigned short* HBh, unsigned short* HBl,
    unsigned short* UBh, unsigned short* UBl)
{
    __shared__ float tile[64][65];
    const int id = blockIdx.x;
    const int t  = threadIdx.x;
    if (id < 256) {                                   // hidden [1024][1024]
        prep_a_body(hidden, HAh, HAl, HIDDEN, id >> 4, id & 15, t);
    } else if (id < 256 + 1568) {                     // feats [3136][2048]
        const int j = id - 256;
        prep_a_body(feats, FAh, FAl, ATT_FEAT, j >> 5, j & 31, t);
    } else if (id < 256 + 1568 + 128) {               // w_h [1024][512]
        const int j = id - (256 + 1568);
        prep_b_body(w_h, HBh, HBl, HIDDEN, EMBED, j >> 4, j & 15, t, tile);
    } else {                                          // w_u [2048][512]
        const int j = id - (256 + 1568 + 128);
        prep_b_body(w_u, UBh, UBl, ATT_FEAT, EMBED, j >> 5, j & 31, t, tile);
    }
}

// ---------------------------------------------------------------------------
// uber GEMM: K1 (128 tiles) + K2 (392 tiles) in one 520-block dispatch.
// Split-bf16, both operands pre-tiled; staging = global_load_lds w16;
// 32x32x16 MFMA; counted-vmcnt double buffer; XCD-bijective swizzle (520/8=65).
// Epilogue: C = (acc + bias) * KCONST   (scores pre-scale, bias fold).
// ---------------------------------------------------------------------------
__global__ __launch_bounds__(256) void uber_gemm(
    const unsigned short* __restrict__ HAh, const unsigned short* __restrict__ HAl,
    const unsigned short* __restrict__ HBh, const unsigned short* __restrict__ HBl,
    const unsigned short* __restrict__ FAh, const unsigned short* __restrict__ FAl,
    const unsigned short* __restrict__ UBh, const unsigned short* __restrict__ UBl,
    const float* __restrict__ bvec, float* __restrict__ Wh, float* __restrict__ Uv)
{
    __shared__ __align__(16) unsigned short L[4][2][4096];   // 64 KB

    const int hh = blockIdx.x;
    const int t0 = (hh & 7) * 65 + (hh >> 3);                // bijective, G=520

    const unsigned short *Ah, *Al, *Bh, *Bl;
    const float* bias;
    float* C;
    int ktiles, rt, ct;
    if (t0 < 128) {            // K1: Wh = hidden @ w_h
        Ah = HAh; Al = HAl; Bh = HBh; Bl = HBl;
        bias = nullptr; C = Wh; ktiles = HIDDEN >> 6;
        rt = t0 >> 3; ct = t0 & 7;
    } else {                   // K2: Uv = feats @ w_u + b
        const int u = t0 - 128;
        Ah = FAh; Al = FAl; Bh = UBh; Bl = UBl;
        bias = bvec; C = Uv; ktiles = ATT_FEAT >> 6;
        rt = u >> 3; ct = u & 7;
    }
    const int N = EMBED;

    const int tid = threadIdx.x, lane = tid & 63, w = tid >> 6;
    const int wr = w >> 1, wc = w & 1;
    const int l31 = lane & 31, kh = lane >> 5;

    const unsigned short* srcMat = (w == 0) ? Ah : (w == 1) ? Al : (w == 2) ? Bh : Bl;
    const int majorTile = (w < 2) ? rt : ct;
    const unsigned short* src0 = srcMat + (size_t)majorTile * ktiles * 4096 + lane * 8;

    f32x16 acc = {};

    auto stage = [&](int buf, int t) {
        const unsigned short* s = src0 + (size_t)t * 4096;
        unsigned short* d = &L[w][buf][0];
        #pragma unroll
        for (int c = 0; c < 8; ++c)
            gl_lds16(s + c * 512, d + c * 512);
    };

    auto compute = [&](int buf) {
        #pragma unroll
        for (int s = 0; s < 4; ++s) {
            const int offA = ((s * 2 + kh) * 64 + wr * 32 + l31) * 8;
            const int offB = ((s * 2 + kh) * 64 + wc * 32 + l31) * 8;
            short8 ah = *(const short8*)&L[0][buf][offA];
            short8 al = *(const short8*)&L[1][buf][offA];
            short8 bh = *(const short8*)&L[2][buf][offB];
            short8 bl = *(const short8*)&L[3][buf][offB];
            acc = __builtin_amdgcn_mfma_f32_32x32x16_bf16(ah, bh, acc, 0, 0, 0);
            acc = __builtin_amdgcn_mfma_f32_32x32x16_bf16(ah, bl, acc, 0, 0, 0);
            acc = __builtin_amdgcn_mfma_f32_32x32x16_bf16(al, bh, acc, 0, 0, 0);
        }
    };

    stage(0, 0);
    for (int t = 0; t < ktiles; ++t) {
        const int cur = t & 1;
        if (t + 1 < ktiles) {
            stage(cur ^ 1, t + 1);
            asm volatile("s_waitcnt vmcnt(8)" ::: "memory");
        } else {
            asm volatile("s_waitcnt vmcnt(0)" ::: "memory");
        }
        __builtin_amdgcn_s_barrier();
        __builtin_amdgcn_sched_barrier(0);
        compute(cur);
        __builtin_amdgcn_sched_barrier(0);
        __builtin_amdgcn_s_barrier();
    }

    // epilogue: col=lane&31, row=(reg&3)+8*(reg>>2)+4*(lane>>5); pre-scale KC
    const int row0 = rt * 64 + wr * 32;
    const int colg = ct * 64 + wc * 32 + l31;
    const float bv = bias ? bias[colg] : 0.f;
    #pragma unroll
    for (int r = 0; r < 16; ++r) {
        const int row = (r & 3) + 8 * (r >> 2) + 4 * kh;
        C[(size_t)(row0 + row) * N + colg] = (acc[r] + bv) * KCONST;
    }
}

// ---------------------------------------------------------------------------
// scores[b,s,n] = 2 * sum_e w[e] / (1 + exp2(Wh'+Uv'))    (inputs pre-scaled
// by KC, bias folded); mask==0 -> -1e9. Writes to scratch (d_ws).
// ---------------------------------------------------------------------------
__global__ __launch_bounds__(256) void scores_kernel(
    const float* __restrict__ Wh, const float* __restrict__ Uv,
    const float* __restrict__ wvec, const int* __restrict__ mask,
    float* __restrict__ scores)
{
    const int n0 = blockIdx.x * 16;
    const int s0 = blockIdx.y * 16;
    const int b  = blockIdx.z;
    const int tid = threadIdx.x;
    const int tx = tid & 15;
    const int ty = tid >> 4;

    __shared__ float whs[16][64];
    __shared__ float uvs[16][64];

    const int r  = tid >> 4;
    const int c4 = tid & 15;
    const int sr = s0 + r;
    const int nr_raw = n0 + r;
    const int nr = nr_raw < NKEY ? nr_raw : NKEY - 1;

    const float* WhRow = Wh + (size_t)(b * SEQ + sr) * EMBED;
    const float* UvRow = Uv + (size_t)(b * NKEY + nr) * EMBED;

    float acc0 = 0.f, acc1 = 0.f, acc2 = 0.f, acc3 = 0.f;

    for (int e0 = 0; e0 < EMBED; e0 += 64) {
        float4v wv = *(const float4v*)(WhRow + e0 + c4 * 4);
        float4v uv = *(const float4v*)(UvRow + e0 + c4 * 4);
        *(float4v*)&whs[r][(c4 ^ r) << 2] = wv;
        *(float4v*)&uvs[r][(c4 ^ r) << 2] = uv;
        __syncthreads();

        #pragma unroll
        for (int c = 0; c < 16; ++c) {
            float4v whv = *(const float4v*)&whs[ty][(c ^ ty) << 2];
            float4v uvv = *(const float4v*)&uvs[tx][(c ^ tx) << 2];
            const float w0 = wvec[e0 + c * 4 + 0];
            const float w1 = wvec[e0 + c * 4 + 1];
            const float w2 = wvec[e0 + c * 4 + 2];
            const float w3 = wvec[e0 + c * 4 + 3];
            float t0 = __builtin_amdgcn_exp2f(whv.x + uvv.x);
            float t1 = __builtin_amdgcn_exp2f(whv.y + uvv.y);
            float t2 = __builtin_amdgcn_exp2f(whv.z + uvv.z);
            float t3 = __builtin_amdgcn_exp2f(whv.w + uvv.w);
            acc0 = fmaf(w0, __builtin_amdgcn_rcpf(1.f + t0), acc0);
            acc1 = fmaf(w1, __builtin_amdgcn_rcpf(1.f + t1), acc1);
            acc2 = fmaf(w2, __builtin_amdgcn_rcpf(1.f + t2), acc2);
            acc3 = fmaf(w3, __builtin_amdgcn_rcpf(1.f + t3), acc3);
        }
        __syncthreads();
    }

    float sc = 2.f * ((acc0 + acc1) + (acc2 + acc3));
    const int n = n0 + tx;
    if (n < NKEY) {
        float v = (mask[b * NKEY + n] == 0) ? -1e9f : sc;
        scores[(size_t)(b * SEQ + s0 + ty) * NKEY + n] = v;
    }
}

// ---------------------------------------------------------------------------
// attn + softmax fused: block covers 8 s-rows x full N for one b.
// 1) row softmax of masked scores (32 lanes/row), write weights (x==0 blocks)
// 2) attn = weights @ feats over 1024 f-cols (float4/lane).
// Grid (2, 8, 16).
// ---------------------------------------------------------------------------
__global__ __launch_bounds__(256) void attn_softmax_kernel(
    const float* __restrict__ scores, const float* __restrict__ feats,
    float* __restrict__ weights_out, float* __restrict__ out)
{
    const int t   = threadIdx.x;
    const int fb  = blockIdx.x;
    const int s0  = blockIdx.y * 8;
    const int b   = blockIdx.z;

    __shared__ float wt[NKEY][8];   // wt[n][s]

    // ---- softmax: row r handled by 32 lanes ----
    {
        const int r  = t >> 5;          // 0..7
        const int ln = t & 31;
        const float* srow = scores + (size_t)(b * SEQ + s0 + r) * NKEY;
        float v[7];
        float mx = -INFINITY;
        #pragma unroll
        for (int j = 0; j < 7; ++j) {
            const int n = ln + 32 * j;
            v[j] = (n < NKEY) ? srow[n] : -INFINITY;
            mx = fmaxf(mx, v[j]);
        }
        #pragma unroll
        for (int off = 16; off; off >>= 1) mx = fmaxf(mx, __shfl_xor(mx, off));
        float sum = 0.f;
        #pragma unroll
        for (int j = 0; j < 7; ++j) {
            v[j] = __builtin_amdgcn_exp2f((v[j] - mx) * LOG2E);
            if (ln + 32 * j < NKEY) sum += v[j];
        }
        #pragma unroll
        for (int off = 16; off; off >>= 1) sum += __shfl_xor(sum, off);
        const float inv = __builtin_amdgcn_rcpf(sum);
        float* wrow = weights_out + (size_t)(b * SEQ + s0 + r) * NKEY;
        #pragma unroll
        for (int j = 0; j < 7; ++j) {
            const int n = ln + 32 * j;
            if (n < NKEY) {
                const float wv = v[j] * inv;
                wt[n][r] = wv;
                if (fb == 0) wrow[n] = wv;
            }
        }
    }
    __syncthreads();

    // ---- attn ----
    const int col = fb * 1024 + t * 4;
    const float* fp = feats + (size_t)b * NKEY * ATT_FEAT + col;

    float4v acc[8] = {};
    #pragma unroll 4
    for (int n = 0; n < NKEY; ++n) {
        float4v f  = *(const float4v*)(fp + (size_t)n * ATT_FEAT);
        float4v w0 = *(const float4v*)&wt[n][0];
        float4v w1 = *(const float4v*)&wt[n][4];
        acc[0] += w0.x * f;
        acc[1] += w0.y * f;
        acc[2] += w0.z * f;
        acc[3] += w0.w * f;
        acc[4] += w1.x * f;
        acc[5] += w1.y * f;
        acc[6] += w1.z * f;
        acc[7] += w1.w * f;
    }

    float* op = out + (size_t)(b * SEQ + s0) * ATT_FEAT + col;
    #pragma unroll
    for (int s = 0; s < 8; ++s)
        *(float4v*)(op + (size_t)s * ATT_FEAT) = acc[s];
}

// ---------------------------------------------------------------------------
extern "C" void kernel_launch(void* const* d_in, const int* in_sizes, int n_in,
                              void* d_out, int out_size, void* d_ws, size_t ws_size,
                              hipStream_t stream)
{
    const float* hidden = (const float*)d_in[0];
    const float* feats  = (const float*)d_in[1];
    const int*   mask   = (const int*)  d_in[2];
    const float* w_h    = (const float*)d_in[3];
    const float* w_u    = (const float*)d_in[4];
    const float* bvec   = (const float*)d_in[5];
    const float* wvec   = (const float*)d_in[6];

    float* out         = (float*)d_out;
    float* attn_out    = out;
    float* weights_out = out + (size_t)BATCH * SEQ * ATT_FEAT;

    // workspace layout (~46 MB)
    float* Wh  = (float*)d_ws;                                   // 1024x512 f32
    float* Uv  = Wh + (size_t)BATCH * SEQ * EMBED;               // 3136x512 f32
    float* scr = Uv + (size_t)BATCH * NKEY * EMBED;              // raw scores
    unsigned short* FAh = (unsigned short*)(scr + (size_t)BATCH * SEQ * NKEY);
    unsigned short* FAl = FAh + (size_t)BATCH * NKEY * ATT_FEAT;
    unsigned short* HAh = FAl + (size_t)BATCH * NKEY * ATT_FEAT;
    unsigned short* HAl = HAh + (size_t)BATCH * SEQ * HIDDEN;
    unsigned short* UBh = HAl + (size_t)BATCH * SEQ * HIDDEN;
    unsigned short* UBl = UBh + (size_t)EMBED * ATT_FEAT;
    unsigned short* HBh = UBl + (size_t)EMBED * ATT_FEAT;
    unsigned short* HBl = HBh + (size_t)EMBED * HIDDEN;

    // 1) all preps (2208 blocks)
    uber_prep<<<dim3(256 + 1568 + 128 + 256), 256, 0, stream>>>(
        hidden, feats, w_h, w_u, HAh, HAl, FAh, FAl, HBh, HBl, UBh, UBl);

    // 2) both GEMMs (520 blocks), outputs pre-scaled by KC, bias folded
    uber_gemm<<<dim3(520), 256, 0, stream>>>(
        HAh, HAl, HBh, HBl, FAh, FAl, UBh, UBl, bvec, Wh, Uv);

    // 3) scores (+mask) -> scratch
    scores_kernel<<<dim3((NKEY + 15) / 16, SEQ / 16, BATCH), 256, 0, stream>>>(
        Wh, Uv, wvec, mask, scr);

    // 4) softmax + weights write + attn
    attn_softmax_kernel<<<dim3(ATT_FEAT / 1024, SEQ / 8, BATCH), 256, 0, stream>>>(
        scr, feats, weights_out, attn_out);
}